// Round 2
// baseline (2855.569 us; speedup 1.0000x reference)
//
#include <hip/hip_runtime.h>
#include <hip/hip_bf16.h>

// AttnDecoderRNN on MI355X.
// Pipeline: pack weights (bf16 MFMA-frag layout) -> embed -> g1 GEMM ->
// LSTM1 (persistent, per-batch-slice) -> g2 GEMM -> LSTM2 -> fused
// attention+softmax+applied -> W1 K-split GEMM -> reduce -> MLP tail.
// R1: lstm_layer rework — transposed gate buffer (kills 8-way LDS bank
// conflicts), G prefetch before MFMA phase, vectorized elementwise.

#define B_    1000
#define T_    101
#define E_    256
#define H_    256
#define BPAD  1008      // 63 * 16
#define MPAD  101824    // 1591 * 64  >= BPAD*T_ = 101808
#define NG    1024      // 4H

typedef __bf16 bf16;
typedef __bf16 bf16x8 __attribute__((ext_vector_type(8)));
typedef float  f32x4  __attribute__((ext_vector_type(4)));

__device__ __forceinline__ bf16 f2b(float f){
  unsigned u = __builtin_bit_cast(unsigned, f);
  u += 0x7FFFu + ((u >> 16) & 1u);               // RNE
  unsigned short h = (unsigned short)(u >> 16);
  return __builtin_bit_cast(bf16, h);
}
__device__ __forceinline__ float b2f(bf16 v){
  unsigned short s = __builtin_bit_cast(unsigned short, v);
  unsigned u = ((unsigned)s) << 16;
  return __builtin_bit_cast(float, u);
}
__device__ __forceinline__ float sigm(float x){ return 1.f/(1.f + __expf(-x)); }
__device__ __forceinline__ float tanh_(float x){ return 2.f/(1.f + __expf(-2.f*x)) - 1.f; }

// ---- pack W[N][K] f32 -> Bp[K/32][N][32] bf16 (MFMA B-fragment order) ----
// dst[q][n][kk] = src[n][q*32+kk]; batched via blockIdx.y.
__global__ void pack_bT(const float* __restrict__ src, bf16* __restrict__ dst,
                        int N, int K)
{
  const long batch = blockIdx.y;
  src += batch * (long)N * K;
  dst += batch * (long)(K/32) * N * 32;
  const int tid = blockIdx.x * blockDim.x + threadIdx.x;
  const int total = (K/32) * N * 4;
  if (tid >= total) return;
  const int kkc = tid & 3;
  const int rem = tid >> 2;
  const int n = rem % N;
  const int q = rem / N;
  const float* s = src + (long)n*K + q*32 + kkc*8;
  bf16x8 v;
  #pragma unroll
  for (int e=0;e<8;e++) v[e] = f2b(s[e]);
  *reinterpret_cast<bf16x8*>(dst + ((long)q*N + n)*32 + kkc*8) = v;
}

// ---- f32 transpose: dst[k][j] = src[j][k], src is [N][K] ----
__global__ void tr_f32(const float* __restrict__ src, float* __restrict__ dst,
                       int N, int K)
{
  const int id = blockIdx.x * blockDim.x + threadIdx.x;
  if (id >= N*K) return;
  const int k = id / N, j = id % N;
  dst[(long)k*N + j] = src[(long)j*K + k];
}

__global__ void bias_sum(const float* __restrict__ a, const float* __restrict__ b,
                         float* __restrict__ o, int n)
{
  const int i = blockIdx.x * blockDim.x + threadIdx.x;
  if (i < n) o[i] = a[i] + b[i];
}

// ---- embedding gather -> x bf16 [MPAD][256], zeros for pad rows ----
__global__ void embed_k(const int* __restrict__ ids, const float* __restrict__ emb,
                        bf16* __restrict__ x)
{
  const int tid = blockIdx.x * blockDim.x + threadIdx.x;   // MPAD*32 exact
  const int m = tid >> 5;
  const int c = (tid & 31) << 3;
  bf16x8 v;
  if (m < B_*T_) {
    const int id = ids[m];
    const float* e = emb + (long)id*E_ + c;
    #pragma unroll
    for (int j=0;j<8;j++) v[j] = f2b(e[j]);
  } else {
    #pragma unroll
    for (int j=0;j<8;j++) v[j] = f2b(0.f);
  }
  *reinterpret_cast<bf16x8*>(x + (long)m*256 + c) = v;
}

// ---- gates GEMM: G[m][1024] = A[m][256] @ Bp + bias, bf16 out ----
// tile 64x1024, 8 waves (each 64x128), K=256.
__launch_bounds__(512)
__global__ void gemm_gates(const bf16* __restrict__ A, const bf16* __restrict__ Bp,
                           const float* __restrict__ bias, bf16* __restrict__ Gout)
{
  __shared__ __align__(16) bf16 smem[17408];   // A: 64x264 ; epilogue stage: 8 x 16x136
  const int m0 = blockIdx.x * 64;
  const int tid = threadIdx.x;
  const int wave = tid >> 6;
  const int lane = tid & 63;
  const int l16 = lane & 15, lg = lane >> 4;

  for (int i = tid; i < 2048; i += 512){
    const int r = i >> 5, cc = (i & 31) << 3;
    *reinterpret_cast<bf16x8*>(&smem[r*264 + cc]) =
      *reinterpret_cast<const bf16x8*>(A + (long)(m0 + r)*256 + cc);
  }
  __syncthreads();

  f32x4 acc[4][8];
  #pragma unroll
  for (int ms=0; ms<4; ++ms)
    #pragma unroll
    for (int ns=0; ns<8; ++ns) acc[ms][ns] = f32x4{0.f,0.f,0.f,0.f};

  const bf16* bb = Bp + ((long)(wave*128 + l16) * 32 + lg*8);
  #pragma unroll 2
  for (int q=0; q<8; ++q){
    bf16x8 af[4];
    #pragma unroll
    for (int ms=0; ms<4; ++ms)
      af[ms] = *reinterpret_cast<const bf16x8*>(&smem[(ms*16 + l16)*264 + q*32 + lg*8]);
    bf16x8 bfr[8];
    #pragma unroll
    for (int ns=0; ns<8; ++ns)
      bfr[ns] = *reinterpret_cast<const bf16x8*>(bb + ((long)q*NG + ns*16) * 32);
    #pragma unroll
    for (int ms=0; ms<4; ++ms)
      #pragma unroll
      for (int ns=0; ns<8; ++ns)
        acc[ms][ns] = __builtin_amdgcn_mfma_f32_16x16x32_bf16(af[ms], bfr[ns], acc[ms][ns], 0,0,0);
  }

  float bv[8];
  #pragma unroll
  for (int ns=0; ns<8; ++ns) bv[ns] = bias[wave*128 + ns*16 + l16];

  bf16* stage = smem + wave*2176;
  #pragma unroll
  for (int ms=0; ms<4; ++ms){
    __syncthreads();      // ms=0: all waves done with A; ms>0: stage reads done
    #pragma unroll
    for (int ns=0; ns<8; ++ns)
      #pragma unroll
      for (int r=0; r<4; ++r)
        stage[(lg*4 + r)*136 + ns*16 + l16] = f2b(acc[ms][ns][r] + bv[ns]);
    __syncthreads();
    const int row = lane >> 2, ch = lane & 3;
    bf16* gout = Gout + (long)(m0 + ms*16 + row)*NG + wave*128;
    #pragma unroll
    for (int cc2=0; cc2<4; ++cc2){
      const int chunk = ch + cc2*4;
      *reinterpret_cast<bf16x8*>(gout + chunk*8) =
        *reinterpret_cast<const bf16x8*>(&stage[row*136 + chunk*8]);
    }
  }
}

// ---- persistent LSTM layer: 63 WGs x 16 batch rows, loop t=0..100 ----
// R1: transposed gate buffer gbufT[1024][17] (conflict-free elementwise),
// G prefetched before MFMA phase, fully vectorized elementwise phase.
__launch_bounds__(512)
__global__ void lstm_layer(const bf16* __restrict__ G, const bf16* __restrict__ Bp,
                           bf16* __restrict__ Hout)
{
  __shared__ __align__(16) bf16 hbuf[16*264];   // current h, bf16, padded rows
  __shared__ float gbufT[1024*17];               // gate partials, transposed [col][row]
  const int b0 = blockIdx.x * 16;
  const int tid = threadIdx.x;
  const int wave = tid >> 6, lane = tid & 63;
  const int l16 = lane & 15, lg = lane >> 4;
  const int row8 = tid & 15;     // elementwise: my batch row
  const int cg   = tid >> 4;     // elementwise: my 8-col group (0..31)

  for (int i = tid; i < 16*264; i += 512) hbuf[i] = f2b(0.f);
  float c[8];
  #pragma unroll
  for (int e=0;e<8;e++) c[e] = 0.f;
  const bf16* bb = Bp + ((long)(wave*128 + l16) * 32 + lg*8);
  const int arow = l16*264 + lg*8;
  const bf16* gbase = G + ((long)(b0 + row8)*T_)*NG + cg*8;
  bf16*       hout  = Hout + ((long)(b0 + row8)*T_)*256 + cg*8;
  __syncthreads();

  for (int t = 0; t < T_; ++t){
    // --- G prefetch (independent of recurrence; hides under MFMA phase) ---
    const bf16* gp = gbase + (long)t*NG;
    const bf16x8 gi = *reinterpret_cast<const bf16x8*>(gp);
    const bf16x8 gf = *reinterpret_cast<const bf16x8*>(gp + 256);
    const bf16x8 gg = *reinterpret_cast<const bf16x8*>(gp + 512);
    const bf16x8 go = *reinterpret_cast<const bf16x8*>(gp + 768);

    // --- recurrent GEMM: 16x1024 += h(16x256) @ Whh^T ---
    f32x4 acc[8];
    #pragma unroll
    for (int ns=0; ns<8; ++ns) acc[ns] = f32x4{0.f,0.f,0.f,0.f};
    #pragma unroll 2
    for (int q=0; q<8; ++q){
      bf16x8 a = *reinterpret_cast<const bf16x8*>(&hbuf[arow + q*32]);
      #pragma unroll
      for (int ns=0; ns<8; ++ns){
        bf16x8 bv = *reinterpret_cast<const bf16x8*>(bb + ((long)q*NG + ns*16) * 32);
        acc[ns] = __builtin_amdgcn_mfma_f32_16x16x32_bf16(a, bv, acc[ns], 0,0,0);
      }
    }
    // transposed store: gbufT[gatecol][row], ~2-way banks
    #pragma unroll
    for (int ns=0; ns<8; ++ns){
      float* gc = &gbufT[(wave*128 + ns*16 + l16)*17 + lg*4];
      gc[0] = acc[ns][0]; gc[1] = acc[ns][1]; gc[2] = acc[ns][2]; gc[3] = acc[ns][3];
    }
    __syncthreads();   // gates visible; all hbuf reads done

    // --- elementwise: thread owns (row8, cols cg*8..cg*8+7) ---
    {
      bf16x8 hv;
      #pragma unroll
      for (int e=0;e<8;e++){
        const int hc = cg*8 + e;
        const float iv = sigm (b2f(gi[e]) + gbufT[(hc      )*17 + row8]);
        const float fv = sigm (b2f(gf[e]) + gbufT[(hc + 256)*17 + row8]);
        const float gv = tanh_(b2f(gg[e]) + gbufT[(hc + 512)*17 + row8]);
        const float ov = sigm (b2f(go[e]) + gbufT[(hc + 768)*17 + row8]);
        c[e] = fv*c[e] + iv*gv;
        hv[e] = f2b(ov * tanh_(c[e]));
      }
      *reinterpret_cast<bf16x8*>(&hbuf[row8*264 + cg*8]) = hv;
      *reinterpret_cast<bf16x8*>(hout + (long)t*256) = hv;
    }
    __syncthreads();   // h updated before next step's reads
  }
}

// ---- fused attention GEMM + softmax + applied (w*x) + flat bf16 ----
__launch_bounds__(256)
__global__ void attn_applied(const bf16* __restrict__ H2, const bf16* __restrict__ Wap,
                             const float* __restrict__ battn, const int* __restrict__ ids,
                             const float* __restrict__ emb, float* __restrict__ applied,
                             bf16* __restrict__ flat)
{
  __shared__ __align__(16) bf16 albuf[32*264];
  __shared__ float sbuf[32*257];
  const int mt = blockIdx.x, t = blockIdx.y;
  const int b0 = mt*32;
  const int tid = threadIdx.x;
  const int wave = tid >> 6, lane = tid & 63;
  const int l16 = lane & 15, lg = lane >> 4;

  for (int i = tid; i < 1024; i += 256){
    const int r = i >> 5, cc = (i & 31) << 3;
    const int b = b0 + r;
    bf16x8 v;
    if (b < B_) v = *reinterpret_cast<const bf16x8*>(H2 + ((long)b*T_ + t)*256 + cc);
    else { 
      #pragma unroll
      for (int j=0;j<8;j++) v[j] = f2b(0.f);
    }
    *reinterpret_cast<bf16x8*>(&albuf[r*264 + cc]) = v;
  }
  __syncthreads();

  f32x4 acc[2][4];
  #pragma unroll
  for (int ms=0; ms<2; ++ms)
    #pragma unroll
    for (int ns=0; ns<4; ++ns) acc[ms][ns] = f32x4{0.f,0.f,0.f,0.f};

  const bf16* bb = Wap + (long)t*65536 + ((long)(wave*64 + l16) * 32 + lg*8);
  #pragma unroll 2
  for (int q=0; q<8; ++q){
    bf16x8 a0 = *reinterpret_cast<const bf16x8*>(&albuf[l16*264 + q*32 + lg*8]);
    bf16x8 a1 = *reinterpret_cast<const bf16x8*>(&albuf[(16 + l16)*264 + q*32 + lg*8]);
    #pragma unroll
    for (int ns=0; ns<4; ++ns){
      bf16x8 b = *reinterpret_cast<const bf16x8*>(bb + ((long)q*256 + ns*16) * 32);
      acc[0][ns] = __builtin_amdgcn_mfma_f32_16x16x32_bf16(a0, b, acc[0][ns], 0,0,0);
      acc[1][ns] = __builtin_amdgcn_mfma_f32_16x16x32_bf16(a1, b, acc[1][ns], 0,0,0);
    }
  }
  float bv[4];
  #pragma unroll
  for (int ns=0; ns<4; ++ns) bv[ns] = battn[t*256 + wave*64 + ns*16 + l16];
  #pragma unroll
  for (int ms=0; ms<2; ++ms)
    #pragma unroll
    for (int ns=0; ns<4; ++ns)
      #pragma unroll
      for (int r=0; r<4; ++r)
        sbuf[(ms*16 + lg*4 + r)*257 + wave*64 + ns*16 + l16] = acc[ms][ns][r] + bv[ns];
  __syncthreads();

  const int row = tid >> 3, seg = tid & 7;
  const float* srow = &sbuf[row*257 + seg*32];
  float v[32];
  float mx = -1e30f;
  #pragma unroll
  for (int i=0;i<32;++i){ v[i] = srow[i]; mx = fmaxf(mx, v[i]); }
  #pragma unroll
  for (int off=1; off<8; off<<=1) mx = fmaxf(mx, __shfl_xor(mx, off));
  float s = 0.f;
  #pragma unroll
  for (int i=0;i<32;++i){ v[i] = __expf(v[i] - mx); s += v[i]; }
  #pragma unroll
  for (int off=1; off<8; off<<=1) s += __shfl_xor(s, off);
  const float inv = 1.f / s;
  const int b = b0 + row;
  if (b < B_){
    const int id = ids[b*T_ + t];
    const float* ex = emb + (long)id*256 + seg*32;
    float* ap = applied + ((long)b*T_ + t)*256 + seg*32;
    bf16* fp = flat + (long)b*25856 + t*256 + seg*32;
    #pragma unroll
    for (int i=0;i<32;++i){
      const float val = v[i]*inv*ex[i];
      ap[i] = val;
      fp[i] = f2b(val);
    }
  }
}

// ---- W1 GEMM: part[ks][m][n] = flat[m][ks-slice] @ W1p, K-split 8 ----
__launch_bounds__(512)
__global__ void gemm_mlp1(const bf16* __restrict__ A, const bf16* __restrict__ Bp,
                          float* __restrict__ part)
{
  const int m0 = blockIdx.x * 32;
  const int ks = blockIdx.y;
  const int tid = threadIdx.x;
  const int wave = tid >> 6, lane = tid & 63;
  const int l16 = lane & 15, lg = lane >> 4;
  f32x4 acc[2][4];
  #pragma unroll
  for (int ms=0; ms<2; ++ms)
    #pragma unroll
    for (int ns=0; ns<4; ++ns) acc[ms][ns] = f32x4{0.f,0.f,0.f,0.f};

  const bf16* arow0 = A + (long)(m0 + l16)*25856 + lg*8;
  const bf16* arow1 = A + (long)(m0 + 16 + l16)*25856 + lg*8;
  const bf16* bb = Bp + ((long)(wave*64 + l16) * 32 + lg*8);
  #pragma unroll 2
  for (int q = ks*101; q < ks*101 + 101; ++q){
    bf16x8 a0 = *reinterpret_cast<const bf16x8*>(arow0 + (long)q*32);
    bf16x8 a1 = *reinterpret_cast<const bf16x8*>(arow1 + (long)q*32);
    #pragma unroll
    for (int ns=0; ns<4; ++ns){
      bf16x8 b = *reinterpret_cast<const bf16x8*>(bb + ((long)q*512 + ns*16) * 32);
      acc[0][ns] = __builtin_amdgcn_mfma_f32_16x16x32_bf16(a0, b, acc[0][ns], 0,0,0);
      acc[1][ns] = __builtin_amdgcn_mfma_f32_16x16x32_bf16(a1, b, acc[1][ns], 0,0,0);
    }
  }
  #pragma unroll
  for (int ms=0; ms<2; ++ms)
    #pragma unroll
    for (int ns=0; ns<4; ++ns)
      #pragma unroll
      for (int r=0; r<4; ++r)
        part[((long)ks*1024 + m0 + ms*16 + lg*4 + r)*512 + wave*64 + ns*16 + l16] = acc[ms][ns][r];
}

__global__ void reduce_relu(const float* __restrict__ part, const float* __restrict__ b1,
                            float* __restrict__ d1)
{
  const int idx = blockIdx.x*256 + threadIdx.x;   // 524288 exact
  const int n = idx & 511, m = idx >> 9;
  float s = b1[n];
  #pragma unroll
  for (int k=0;k<8;k++) s += part[((long)k*1024 + m)*512 + n];
  d1[idx] = fmaxf(s, 0.f);
}

// ---- MLP layers 2..4 fused, one block per batch row ----
__launch_bounds__(128)
__global__ void mlp_tail(const float* __restrict__ d1, const float* __restrict__ W2T,
                         const float* __restrict__ b2, const float* __restrict__ W3T,
                         const float* __restrict__ b3, const float* __restrict__ Wout,
                         const float* __restrict__ bout, float* __restrict__ tag)
{
  __shared__ float r1[512];
  __shared__ float r2[128];
  __shared__ float r3[64];
  const int b = blockIdx.x;
  const int tid = threadIdx.x;
  for (int i = tid; i < 512; i += 128) r1[i] = d1[(long)b*512 + i];
  __syncthreads();
  float a = b2[tid];
  #pragma unroll 8
  for (int k=0;k<512;++k) a += W2T[k*128 + tid] * r1[k];
  r2[tid] = fmaxf(a, 0.f);
  __syncthreads();
  if (tid < 64){
    float a3 = b3[tid];
    #pragma unroll 8
    for (int k=0;k<128;++k) a3 += W3T[k*64 + tid] * r2[k];
    r3[tid] = fmaxf(a3, 0.f);
  }
  __syncthreads();
  if (tid < 64){
    float p = r3[tid] * Wout[tid];
    #pragma unroll
    for (int off=1; off<64; off<<=1) p += __shfl_xor(p, off);
    if (tid == 0) tag[b] = p + bout[0];
  }
}

extern "C" void kernel_launch(void* const* d_in, const int* in_sizes, int n_in,
                              void* d_out, int out_size, void* d_ws, size_t ws_size,
                              hipStream_t stream)
{
  const int*   ids   = (const int*)  d_in[0];
  const float* emb   = (const float*)d_in[1];
  const float* Wih1  = (const float*)d_in[2];
  const float* Whh1  = (const float*)d_in[3];
  const float* bih1  = (const float*)d_in[4];
  const float* bhh1  = (const float*)d_in[5];
  const float* Wih2  = (const float*)d_in[6];
  const float* Whh2  = (const float*)d_in[7];
  const float* bih2  = (const float*)d_in[8];
  const float* bhh2  = (const float*)d_in[9];
  const float* Wattn = (const float*)d_in[10];
  const float* battn = (const float*)d_in[11];
  const float* W1    = (const float*)d_in[12];
  const float* b1    = (const float*)d_in[13];
  const float* W2    = (const float*)d_in[14];
  const float* b2    = (const float*)d_in[15];
  const float* W3    = (const float*)d_in[16];
  const float* b3    = (const float*)d_in[17];
  const float* Wout  = (const float*)d_in[18];
  const float* bout  = (const float*)d_in[19];
  float* out = (float*)d_out;
  char*  ws  = (char*)d_ws;

  // workspace layout (bytes)
  constexpr size_t OW_IH1 = 0;
  constexpr size_t OW_HH1 = 524288;
  constexpr size_t OW_IH2 = 1048576;
  constexpr size_t OW_HH2 = 1572864;
  constexpr size_t OW_ATT = 2097152;     // 13,238,272
  constexpr size_t OW_W1  = 15335424;    // 26,476,544
  constexpr size_t OW_W2T = 41811968;
  constexpr size_t OW_W3T = 42074112;
  constexpr size_t OB1    = 42106880;
  constexpr size_t OB2    = 42110976;
  constexpr size_t OXH2   = 42115072;    // x bf16, later h2 (alias)
  constexpr size_t OG     = 94248960;    // gates (208.5MB); later flat+part alias
  constexpr size_t OFLAT  = OG;
  constexpr size_t OPART  = OG + 52953088;
  constexpr size_t OH1    = 302784512;
  constexpr size_t OD1    = 354918400;
  constexpr size_t NEED   = 357015552;
  if (ws_size < NEED) return;

  bf16*  pIH1 = (bf16*) (ws + OW_IH1);
  bf16*  pHH1 = (bf16*) (ws + OW_HH1);
  bf16*  pIH2 = (bf16*) (ws + OW_IH2);
  bf16*  pHH2 = (bf16*) (ws + OW_HH2);
  bf16*  pATT = (bf16*) (ws + OW_ATT);
  bf16*  pW1  = (bf16*) (ws + OW_W1);
  float* pW2T = (float*)(ws + OW_W2T);
  float* pW3T = (float*)(ws + OW_W3T);
  float* pB1  = (float*)(ws + OB1);
  float* pB2  = (float*)(ws + OB2);
  bf16*  pXH2 = (bf16*) (ws + OXH2);
  bf16*  pG   = (bf16*) (ws + OG);
  bf16*  pFLAT= (bf16*) (ws + OFLAT);
  float* pPART= (float*)(ws + OPART);
  bf16*  pH1  = (bf16*) (ws + OH1);
  float* pD1  = (float*)(ws + OD1);

  // zero h1 pad tail (rows 101808..101823) before g2 GEMM reads it
  hipMemsetAsync(ws + OH1 + (size_t)101808*512, 0, (size_t)16*512, stream);

  // weight packing
  pack_bT<<<dim3(128),        256, 0, stream>>>(Wih1,  pIH1, 1024, 256);
  pack_bT<<<dim3(128),        256, 0, stream>>>(Whh1,  pHH1, 1024, 256);
  pack_bT<<<dim3(128),        256, 0, stream>>>(Wih2,  pIH2, 1024, 256);
  pack_bT<<<dim3(128),        256, 0, stream>>>(Whh2,  pHH2, 1024, 256);
  pack_bT<<<dim3(32, 101),    256, 0, stream>>>(Wattn, pATT, 256,  256);
  pack_bT<<<dim3(6464),       256, 0, stream>>>(W1,    pW1,  512,  25856);
  tr_f32 <<<dim3(256),        256, 0, stream>>>(W2, pW2T, 128, 512);
  tr_f32 <<<dim3(32),         256, 0, stream>>>(W3, pW3T, 64, 128);
  bias_sum<<<dim3(4),         256, 0, stream>>>(bih1, bhh1, pB1, 1024);
  bias_sum<<<dim3(4),         256, 0, stream>>>(bih2, bhh2, pB2, 1024);

  // embed -> x bf16
  embed_k<<<dim3(12728), 256, 0, stream>>>(ids, emb, pXH2);

  // layer 1
  gemm_gates<<<dim3(1591), 512, 0, stream>>>(pXH2, pIH1, pB1, pG);
  lstm_layer<<<dim3(63),   512, 0, stream>>>(pG, pHH1, pH1);
  // layer 2
  gemm_gates<<<dim3(1591), 512, 0, stream>>>(pH1, pIH2, pB2, pG);
  lstm_layer<<<dim3(63),   512, 0, stream>>>(pG, pHH2, pXH2);   // h2 -> XH2 alias

  // flat pad rows [1000,1024) zero (after gates buffer is dead)
  hipMemsetAsync(ws + OFLAT + (size_t)B_*25856*2, 0, (size_t)24*25856*2, stream);

  // attention + softmax + applied (writes d_out applied region + flat bf16)
  attn_applied<<<dim3(32, 101), 256, 0, stream>>>(pXH2, pATT, battn, ids, emb,
                                                  out + 1000, pFLAT);

  // MLP
  gemm_mlp1  <<<dim3(32, 8), 512, 0, stream>>>(pFLAT, pW1, pPART);
  reduce_relu<<<dim3(2048),  256, 0, stream>>>(pPART, b1, pD1);
  mlp_tail   <<<dim3(1000),  128, 0, stream>>>(pD1, pW2T, b2, pW3T, b3, Wout, bout, out);
}

// Round 3
// 2108.861 us; speedup vs baseline: 1.3541x; 1.3541x over previous
//
#include <hip/hip_runtime.h>
#include <hip/hip_bf16.h>

// AttnDecoderRNN on MI355X.
// Pipeline: pack weights (bf16 MFMA-frag layout) -> embed -> g1 GEMM ->
// LSTM1 (persistent, per-batch-slice) -> g2 GEMM -> LSTM2 -> fused
// attention+softmax+applied -> W1 K-split GEMM -> reduce -> MLP tail.
// R1: transposed gate buffer, G prefetch, vectorized elementwise.
// R2: lstm_layer load-latency fix — __launch_bounds__(512,2) (256-VGPR
// budget) + explicit double-buffered B-fragment prefetch pipeline.

#define B_    1000
#define T_    101
#define E_    256
#define H_    256
#define BPAD  1008      // 63 * 16
#define MPAD  101824    // 1591 * 64  >= BPAD*T_ = 101808
#define NG    1024      // 4H

typedef __bf16 bf16;
typedef __bf16 bf16x8 __attribute__((ext_vector_type(8)));
typedef float  f32x4  __attribute__((ext_vector_type(4)));

__device__ __forceinline__ bf16 f2b(float f){
  unsigned u = __builtin_bit_cast(unsigned, f);
  u += 0x7FFFu + ((u >> 16) & 1u);               // RNE
  unsigned short h = (unsigned short)(u >> 16);
  return __builtin_bit_cast(bf16, h);
}
__device__ __forceinline__ float b2f(bf16 v){
  unsigned short s = __builtin_bit_cast(unsigned short, v);
  unsigned u = ((unsigned)s) << 16;
  return __builtin_bit_cast(float, u);
}
__device__ __forceinline__ float sigm(float x){ return 1.f/(1.f + __expf(-x)); }
__device__ __forceinline__ float tanh_(float x){ return 2.f/(1.f + __expf(-2.f*x)) - 1.f; }

// ---- pack W[N][K] f32 -> Bp[K/32][N][32] bf16 (MFMA B-fragment order) ----
// dst[q][n][kk] = src[n][q*32+kk]; batched via blockIdx.y.
__global__ void pack_bT(const float* __restrict__ src, bf16* __restrict__ dst,
                        int N, int K)
{
  const long batch = blockIdx.y;
  src += batch * (long)N * K;
  dst += batch * (long)(K/32) * N * 32;
  const int tid = blockIdx.x * blockDim.x + threadIdx.x;
  const int total = (K/32) * N * 4;
  if (tid >= total) return;
  const int kkc = tid & 3;
  const int rem = tid >> 2;
  const int n = rem % N;
  const int q = rem / N;
  const float* s = src + (long)n*K + q*32 + kkc*8;
  bf16x8 v;
  #pragma unroll
  for (int e=0;e<8;e++) v[e] = f2b(s[e]);
  *reinterpret_cast<bf16x8*>(dst + ((long)q*N + n)*32 + kkc*8) = v;
}

// ---- f32 transpose: dst[k][j] = src[j][k], src is [N][K] ----
__global__ void tr_f32(const float* __restrict__ src, float* __restrict__ dst,
                       int N, int K)
{
  const int id = blockIdx.x * blockDim.x + threadIdx.x;
  if (id >= N*K) return;
  const int k = id / N, j = id % N;
  dst[(long)k*N + j] = src[(long)j*K + k];
}

__global__ void bias_sum(const float* __restrict__ a, const float* __restrict__ b,
                         float* __restrict__ o, int n)
{
  const int i = blockIdx.x * blockDim.x + threadIdx.x;
  if (i < n) o[i] = a[i] + b[i];
}

// ---- embedding gather -> x bf16 [MPAD][256], zeros for pad rows ----
__global__ void embed_k(const int* __restrict__ ids, const float* __restrict__ emb,
                        bf16* __restrict__ x)
{
  const int tid = blockIdx.x * blockDim.x + threadIdx.x;   // MPAD*32 exact
  const int m = tid >> 5;
  const int c = (tid & 31) << 3;
  bf16x8 v;
  if (m < B_*T_) {
    const int id = ids[m];
    const float* e = emb + (long)id*E_ + c;
    #pragma unroll
    for (int j=0;j<8;j++) v[j] = f2b(e[j]);
  } else {
    #pragma unroll
    for (int j=0;j<8;j++) v[j] = f2b(0.f);
  }
  *reinterpret_cast<bf16x8*>(x + (long)m*256 + c) = v;
}

// ---- gates GEMM: G[m][1024] = A[m][256] @ Bp + bias, bf16 out ----
// tile 64x1024, 8 waves (each 64x128), K=256.
__launch_bounds__(512)
__global__ void gemm_gates(const bf16* __restrict__ A, const bf16* __restrict__ Bp,
                           const float* __restrict__ bias, bf16* __restrict__ Gout)
{
  __shared__ __align__(16) bf16 smem[17408];   // A: 64x264 ; epilogue stage: 8 x 16x136
  const int m0 = blockIdx.x * 64;
  const int tid = threadIdx.x;
  const int wave = tid >> 6;
  const int lane = tid & 63;
  const int l16 = lane & 15, lg = lane >> 4;

  for (int i = tid; i < 2048; i += 512){
    const int r = i >> 5, cc = (i & 31) << 3;
    *reinterpret_cast<bf16x8*>(&smem[r*264 + cc]) =
      *reinterpret_cast<const bf16x8*>(A + (long)(m0 + r)*256 + cc);
  }
  __syncthreads();

  f32x4 acc[4][8];
  #pragma unroll
  for (int ms=0; ms<4; ++ms)
    #pragma unroll
    for (int ns=0; ns<8; ++ns) acc[ms][ns] = f32x4{0.f,0.f,0.f,0.f};

  const bf16* bb = Bp + ((long)(wave*128 + l16) * 32 + lg*8);
  #pragma unroll 2
  for (int q=0; q<8; ++q){
    bf16x8 af[4];
    #pragma unroll
    for (int ms=0; ms<4; ++ms)
      af[ms] = *reinterpret_cast<const bf16x8*>(&smem[(ms*16 + l16)*264 + q*32 + lg*8]);
    bf16x8 bfr[8];
    #pragma unroll
    for (int ns=0; ns<8; ++ns)
      bfr[ns] = *reinterpret_cast<const bf16x8*>(bb + ((long)q*NG + ns*16) * 32);
    #pragma unroll
    for (int ms=0; ms<4; ++ms)
      #pragma unroll
      for (int ns=0; ns<8; ++ns)
        acc[ms][ns] = __builtin_amdgcn_mfma_f32_16x16x32_bf16(af[ms], bfr[ns], acc[ms][ns], 0,0,0);
  }

  float bv[8];
  #pragma unroll
  for (int ns=0; ns<8; ++ns) bv[ns] = bias[wave*128 + ns*16 + l16];

  bf16* stage = smem + wave*2176;
  #pragma unroll
  for (int ms=0; ms<4; ++ms){
    __syncthreads();      // ms=0: all waves done with A; ms>0: stage reads done
    #pragma unroll
    for (int ns=0; ns<8; ++ns)
      #pragma unroll
      for (int r=0; r<4; ++r)
        stage[(lg*4 + r)*136 + ns*16 + l16] = f2b(acc[ms][ns][r] + bv[ns]);
    __syncthreads();
    const int row = lane >> 2, ch = lane & 3;
    bf16* gout = Gout + (long)(m0 + ms*16 + row)*NG + wave*128;
    #pragma unroll
    for (int cc2=0; cc2<4; ++cc2){
      const int chunk = ch + cc2*4;
      *reinterpret_cast<bf16x8*>(gout + chunk*8) =
        *reinterpret_cast<const bf16x8*>(&stage[row*136 + chunk*8]);
    }
  }
}

// ---- persistent LSTM layer: 63 WGs x 16 batch rows, loop t=0..100 ----
// R2: 256-VGPR budget + double-buffered B-fragment prefetch pipeline.
#define LOADB_(dst, q_) { \
  _Pragma("unroll") \
  for (int ns=0; ns<8; ++ns) \
    dst[ns] = *reinterpret_cast<const bf16x8*>(bb + ((long)(q_)*NG + ns*16) * 32); }

__launch_bounds__(512, 2)
__global__ void lstm_layer(const bf16* __restrict__ G, const bf16* __restrict__ Bp,
                           bf16* __restrict__ Hout)
{
  __shared__ __align__(16) bf16 hbuf[16*264];   // current h, bf16, padded rows
  __shared__ float gbufT[1024*17];               // gate partials, transposed [col][row]
  const int b0 = blockIdx.x * 16;
  const int tid = threadIdx.x;
  const int wave = tid >> 6, lane = tid & 63;
  const int l16 = lane & 15, lg = lane >> 4;
  const int row8 = tid & 15;     // elementwise: my batch row
  const int cg   = tid >> 4;     // elementwise: my 8-col group (0..31)

  for (int i = tid; i < 16*264; i += 512) hbuf[i] = f2b(0.f);
  float c[8];
  #pragma unroll
  for (int e=0;e<8;e++) c[e] = 0.f;
  const bf16* bb = Bp + ((long)(wave*128 + l16) * 32 + lg*8);
  const int arow = l16*264 + lg*8;
  const bf16* gbase = G + ((long)(b0 + row8)*T_)*NG + cg*8;
  bf16*       hout  = Hout + ((long)(b0 + row8)*T_)*256 + cg*8;
  __syncthreads();

  for (int t = 0; t < T_; ++t){
    // --- G prefetch (independent of recurrence; hides under MFMA phase) ---
    const bf16* gp = gbase + (long)t*NG;
    const bf16x8 gi = *reinterpret_cast<const bf16x8*>(gp);
    const bf16x8 gf = *reinterpret_cast<const bf16x8*>(gp + 256);
    const bf16x8 gg = *reinterpret_cast<const bf16x8*>(gp + 512);
    const bf16x8 go = *reinterpret_cast<const bf16x8*>(gp + 768);

    // --- recurrent GEMM: 16x1024 += h(16x256) @ Whh^T ---
    // B-fragment double-buffer: while MFMA consumes one set of 8 frags,
    // the next q-step's 8 frags are in flight.
    f32x4 acc[8];
    #pragma unroll
    for (int ns=0; ns<8; ++ns) acc[ns] = f32x4{0.f,0.f,0.f,0.f};

    bf16x8 bA[8], bB[8];
    LOADB_(bA, 0);
    #pragma unroll
    for (int h2=0; h2<4; ++h2){
      const int q0 = 2*h2;
      LOADB_(bB, q0+1);
      {
        bf16x8 a = *reinterpret_cast<const bf16x8*>(&hbuf[arow + q0*32]);
        #pragma unroll
        for (int ns=0; ns<8; ++ns)
          acc[ns] = __builtin_amdgcn_mfma_f32_16x16x32_bf16(a, bA[ns], acc[ns], 0,0,0);
      }
      if (q0+2 < 8) LOADB_(bA, q0+2);
      {
        bf16x8 a = *reinterpret_cast<const bf16x8*>(&hbuf[arow + (q0+1)*32]);
        #pragma unroll
        for (int ns=0; ns<8; ++ns)
          acc[ns] = __builtin_amdgcn_mfma_f32_16x16x32_bf16(a, bB[ns], acc[ns], 0,0,0);
      }
    }
    // transposed store: gbufT[gatecol][row], ~2-way banks
    #pragma unroll
    for (int ns=0; ns<8; ++ns){
      float* gc = &gbufT[(wave*128 + ns*16 + l16)*17 + lg*4];
      gc[0] = acc[ns][0]; gc[1] = acc[ns][1]; gc[2] = acc[ns][2]; gc[3] = acc[ns][3];
    }
    __syncthreads();   // gates visible; all hbuf reads done

    // --- elementwise: thread owns (row8, cols cg*8..cg*8+7) ---
    {
      bf16x8 hv;
      #pragma unroll
      for (int e=0;e<8;e++){
        const int hc = cg*8 + e;
        const float iv = sigm (b2f(gi[e]) + gbufT[(hc      )*17 + row8]);
        const float fv = sigm (b2f(gf[e]) + gbufT[(hc + 256)*17 + row8]);
        const float gv = tanh_(b2f(gg[e]) + gbufT[(hc + 512)*17 + row8]);
        const float ov = sigm (b2f(go[e]) + gbufT[(hc + 768)*17 + row8]);
        c[e] = fv*c[e] + iv*gv;
        hv[e] = f2b(ov * tanh_(c[e]));
      }
      *reinterpret_cast<bf16x8*>(&hbuf[row8*264 + cg*8]) = hv;
      *reinterpret_cast<bf16x8*>(hout + (long)t*256) = hv;
    }
    __syncthreads();   // h updated before next step's reads
  }
}

// ---- fused attention GEMM + softmax + applied (w*x) + flat bf16 ----
__launch_bounds__(256)
__global__ void attn_applied(const bf16* __restrict__ H2, const bf16* __restrict__ Wap,
                             const float* __restrict__ battn, const int* __restrict__ ids,
                             const float* __restrict__ emb, float* __restrict__ applied,
                             bf16* __restrict__ flat)
{
  __shared__ __align__(16) bf16 albuf[32*264];
  __shared__ float sbuf[32*257];
  const int mt = blockIdx.x, t = blockIdx.y;
  const int b0 = mt*32;
  const int tid = threadIdx.x;
  const int wave = tid >> 6, lane = tid & 63;
  const int l16 = lane & 15, lg = lane >> 4;

  for (int i = tid; i < 1024; i += 256){
    const int r = i >> 5, cc = (i & 31) << 3;
    const int b = b0 + r;
    bf16x8 v;
    if (b < B_) v = *reinterpret_cast<const bf16x8*>(H2 + ((long)b*T_ + t)*256 + cc);
    else { 
      #pragma unroll
      for (int j=0;j<8;j++) v[j] = f2b(0.f);
    }
    *reinterpret_cast<bf16x8*>(&albuf[r*264 + cc]) = v;
  }
  __syncthreads();

  f32x4 acc[2][4];
  #pragma unroll
  for (int ms=0; ms<2; ++ms)
    #pragma unroll
    for (int ns=0; ns<4; ++ns) acc[ms][ns] = f32x4{0.f,0.f,0.f,0.f};

  const bf16* bb = Wap + (long)t*65536 + ((long)(wave*64 + l16) * 32 + lg*8);
  #pragma unroll 2
  for (int q=0; q<8; ++q){
    bf16x8 a0 = *reinterpret_cast<const bf16x8*>(&albuf[l16*264 + q*32 + lg*8]);
    bf16x8 a1 = *reinterpret_cast<const bf16x8*>(&albuf[(16 + l16)*264 + q*32 + lg*8]);
    #pragma unroll
    for (int ns=0; ns<4; ++ns){
      bf16x8 b = *reinterpret_cast<const bf16x8*>(bb + ((long)q*256 + ns*16) * 32);
      acc[0][ns] = __builtin_amdgcn_mfma_f32_16x16x32_bf16(a0, b, acc[0][ns], 0,0,0);
      acc[1][ns] = __builtin_amdgcn_mfma_f32_16x16x32_bf16(a1, b, acc[1][ns], 0,0,0);
    }
  }
  float bv[4];
  #pragma unroll
  for (int ns=0; ns<4; ++ns) bv[ns] = battn[t*256 + wave*64 + ns*16 + l16];
  #pragma unroll
  for (int ms=0; ms<2; ++ms)
    #pragma unroll
    for (int ns=0; ns<4; ++ns)
      #pragma unroll
      for (int r=0; r<4; ++r)
        sbuf[(ms*16 + lg*4 + r)*257 + wave*64 + ns*16 + l16] = acc[ms][ns][r] + bv[ns];
  __syncthreads();

  const int row = tid >> 3, seg = tid & 7;
  const float* srow = &sbuf[row*257 + seg*32];
  float v[32];
  float mx = -1e30f;
  #pragma unroll
  for (int i=0;i<32;++i){ v[i] = srow[i]; mx = fmaxf(mx, v[i]); }
  #pragma unroll
  for (int off=1; off<8; off<<=1) mx = fmaxf(mx, __shfl_xor(mx, off));
  float s = 0.f;
  #pragma unroll
  for (int i=0;i<32;++i){ v[i] = __expf(v[i] - mx); s += v[i]; }
  #pragma unroll
  for (int off=1; off<8; off<<=1) s += __shfl_xor(s, off);
  const float inv = 1.f / s;
  const int b = b0 + row;
  if (b < B_){
    const int id = ids[b*T_ + t];
    const float* ex = emb + (long)id*256 + seg*32;
    float* ap = applied + ((long)b*T_ + t)*256 + seg*32;
    bf16* fp = flat + (long)b*25856 + t*256 + seg*32;
    #pragma unroll
    for (int i=0;i<32;++i){
      const float val = v[i]*inv*ex[i];
      ap[i] = val;
      fp[i] = f2b(val);
    }
  }
}

// ---- W1 GEMM: part[ks][m][n] = flat[m][ks-slice] @ W1p, K-split 8 ----
__launch_bounds__(512)
__global__ void gemm_mlp1(const bf16* __restrict__ A, const bf16* __restrict__ Bp,
                          float* __restrict__ part)
{
  const int m0 = blockIdx.x * 32;
  const int ks = blockIdx.y;
  const int tid = threadIdx.x;
  const int wave = tid >> 6, lane = tid & 63;
  const int l16 = lane & 15, lg = lane >> 4;
  f32x4 acc[2][4];
  #pragma unroll
  for (int ms=0; ms<2; ++ms)
    #pragma unroll
    for (int ns=0; ns<4; ++ns) acc[ms][ns] = f32x4{0.f,0.f,0.f,0.f};

  const bf16* arow0 = A + (long)(m0 + l16)*25856 + lg*8;
  const bf16* arow1 = A + (long)(m0 + 16 + l16)*25856 + lg*8;
  const bf16* bb = Bp + ((long)(wave*64 + l16) * 32 + lg*8);
  #pragma unroll 2
  for (int q = ks*101; q < ks*101 + 101; ++q){
    bf16x8 a0 = *reinterpret_cast<const bf16x8*>(arow0 + (long)q*32);
    bf16x8 a1 = *reinterpret_cast<const bf16x8*>(arow1 + (long)q*32);
    #pragma unroll
    for (int ns=0; ns<4; ++ns){
      bf16x8 b = *reinterpret_cast<const bf16x8*>(bb + ((long)q*512 + ns*16) * 32);
      acc[0][ns] = __builtin_amdgcn_mfma_f32_16x16x32_bf16(a0, b, acc[0][ns], 0,0,0);
      acc[1][ns] = __builtin_amdgcn_mfma_f32_16x16x32_bf16(a1, b, acc[1][ns], 0,0,0);
    }
  }
  #pragma unroll
  for (int ms=0; ms<2; ++ms)
    #pragma unroll
    for (int ns=0; ns<4; ++ns)
      #pragma unroll
      for (int r=0; r<4; ++r)
        part[((long)ks*1024 + m0 + ms*16 + lg*4 + r)*512 + wave*64 + ns*16 + l16] = acc[ms][ns][r];
}

__global__ void reduce_relu(const float* __restrict__ part, const float* __restrict__ b1,
                            float* __restrict__ d1)
{
  const int idx = blockIdx.x*256 + threadIdx.x;   // 524288 exact
  const int n = idx & 511, m = idx >> 9;
  float s = b1[n];
  #pragma unroll
  for (int k=0;k<8;k++) s += part[((long)k*1024 + m)*512 + n];
  d1[idx] = fmaxf(s, 0.f);
}

// ---- MLP layers 2..4 fused, one block per batch row ----
__launch_bounds__(128)
__global__ void mlp_tail(const float* __restrict__ d1, const float* __restrict__ W2T,
                         const float* __restrict__ b2, const float* __restrict__ W3T,
                         const float* __restrict__ b3, const float* __restrict__ Wout,
                         const float* __restrict__ bout, float* __restrict__ tag)
{
  __shared__ float r1[512];
  __shared__ float r2[128];
  __shared__ float r3[64];
  const int b = blockIdx.x;
  const int tid = threadIdx.x;
  for (int i = tid; i < 512; i += 128) r1[i] = d1[(long)b*512 + i];
  __syncthreads();
  float a = b2[tid];
  #pragma unroll 8
  for (int k=0;k<512;++k) a += W2T[k*128 + tid] * r1[k];
  r2[tid] = fmaxf(a, 0.f);
  __syncthreads();
  if (tid < 64){
    float a3 = b3[tid];
    #pragma unroll 8
    for (int k=0;k<128;++k) a3 += W3T[k*64 + tid] * r2[k];
    r3[tid] = fmaxf(a3, 0.f);
  }
  __syncthreads();
  if (tid < 64){
    float p = r3[tid] * Wout[tid];
    #pragma unroll
    for (int off=1; off<64; off<<=1) p += __shfl_xor(p, off);
    if (tid == 0) tag[b] = p + bout[0];
  }
}

extern "C" void kernel_launch(void* const* d_in, const int* in_sizes, int n_in,
                              void* d_out, int out_size, void* d_ws, size_t ws_size,
                              hipStream_t stream)
{
  const int*   ids   = (const int*)  d_in[0];
  const float* emb   = (const float*)d_in[1];
  const float* Wih1  = (const float*)d_in[2];
  const float* Whh1  = (const float*)d_in[3];
  const float* bih1  = (const float*)d_in[4];
  const float* bhh1  = (const float*)d_in[5];
  const float* Wih2  = (const float*)d_in[6];
  const float* Whh2  = (const float*)d_in[7];
  const float* bih2  = (const float*)d_in[8];
  const float* bhh2  = (const float*)d_in[9];
  const float* Wattn = (const float*)d_in[10];
  const float* battn = (const float*)d_in[11];
  const float* W1    = (const float*)d_in[12];
  const float* b1    = (const float*)d_in[13];
  const float* W2    = (const float*)d_in[14];
  const float* b2    = (const float*)d_in[15];
  const float* W3    = (const float*)d_in[16];
  const float* b3    = (const float*)d_in[17];
  const float* Wout  = (const float*)d_in[18];
  const float* bout  = (const float*)d_in[19];
  float* out = (float*)d_out;
  char*  ws  = (char*)d_ws;

  // workspace layout (bytes)
  constexpr size_t OW_IH1 = 0;
  constexpr size_t OW_HH1 = 524288;
  constexpr size_t OW_IH2 = 1048576;
  constexpr size_t OW_HH2 = 1572864;
  constexpr size_t OW_ATT = 2097152;     // 13,238,272
  constexpr size_t OW_W1  = 15335424;    // 26,476,544
  constexpr size_t OW_W2T = 41811968;
  constexpr size_t OW_W3T = 42074112;
  constexpr size_t OB1    = 42106880;
  constexpr size_t OB2    = 42110976;
  constexpr size_t OXH2   = 42115072;    // x bf16, later h2 (alias)
  constexpr size_t OG     = 94248960;    // gates (208.5MB); later flat+part alias
  constexpr size_t OFLAT  = OG;
  constexpr size_t OPART  = OG + 52953088;
  constexpr size_t OH1    = 302784512;
  constexpr size_t OD1    = 354918400;
  constexpr size_t NEED   = 357015552;
  if (ws_size < NEED) return;

  bf16*  pIH1 = (bf16*) (ws + OW_IH1);
  bf16*  pHH1 = (bf16*) (ws + OW_HH1);
  bf16*  pIH2 = (bf16*) (ws + OW_IH2);
  bf16*  pHH2 = (bf16*) (ws + OW_HH2);
  bf16*  pATT = (bf16*) (ws + OW_ATT);
  bf16*  pW1  = (bf16*) (ws + OW_W1);
  float* pW2T = (float*)(ws + OW_W2T);
  float* pW3T = (float*)(ws + OW_W3T);
  float* pB1  = (float*)(ws + OB1);
  float* pB2  = (float*)(ws + OB2);
  bf16*  pXH2 = (bf16*) (ws + OXH2);
  bf16*  pG   = (bf16*) (ws + OG);
  bf16*  pFLAT= (bf16*) (ws + OFLAT);
  float* pPART= (float*)(ws + OPART);
  bf16*  pH1  = (bf16*) (ws + OH1);
  float* pD1  = (float*)(ws + OD1);

  // zero h1 pad tail (rows 101808..101823) before g2 GEMM reads it
  hipMemsetAsync(ws + OH1 + (size_t)101808*512, 0, (size_t)16*512, stream);

  // weight packing
  pack_bT<<<dim3(128),        256, 0, stream>>>(Wih1,  pIH1, 1024, 256);
  pack_bT<<<dim3(128),        256, 0, stream>>>(Whh1,  pHH1, 1024, 256);
  pack_bT<<<dim3(128),        256, 0, stream>>>(Wih2,  pIH2, 1024, 256);
  pack_bT<<<dim3(128),        256, 0, stream>>>(Whh2,  pHH2, 1024, 256);
  pack_bT<<<dim3(32, 101),    256, 0, stream>>>(Wattn, pATT, 256,  256);
  pack_bT<<<dim3(6464),       256, 0, stream>>>(W1,    pW1,  512,  25856);
  tr_f32 <<<dim3(256),        256, 0, stream>>>(W2, pW2T, 128, 512);
  tr_f32 <<<dim3(32),         256, 0, stream>>>(W3, pW3T, 64, 128);
  bias_sum<<<dim3(4),         256, 0, stream>>>(bih1, bhh1, pB1, 1024);
  bias_sum<<<dim3(4),         256, 0, stream>>>(bih2, bhh2, pB2, 1024);

  // embed -> x bf16
  embed_k<<<dim3(12728), 256, 0, stream>>>(ids, emb, pXH2);

  // layer 1
  gemm_gates<<<dim3(1591), 512, 0, stream>>>(pXH2, pIH1, pB1, pG);
  lstm_layer<<<dim3(63),   512, 0, stream>>>(pG, pHH1, pH1);
  // layer 2
  gemm_gates<<<dim3(1591), 512, 0, stream>>>(pH1, pIH2, pB2, pG);
  lstm_layer<<<dim3(63),   512, 0, stream>>>(pG, pHH2, pXH2);   // h2 -> XH2 alias

  // flat pad rows [1000,1024) zero (after gates buffer is dead)
  hipMemsetAsync(ws + OFLAT + (size_t)B_*25856*2, 0, (size_t)24*25856*2, stream);

  // attention + softmax + applied (writes d_out applied region + flat bf16)
  attn_applied<<<dim3(32, 101), 256, 0, stream>>>(pXH2, pATT, battn, ids, emb,
                                                  out + 1000, pFLAT);

  // MLP
  gemm_mlp1  <<<dim3(32, 8), 512, 0, stream>>>(pFLAT, pW1, pPART);
  reduce_relu<<<dim3(2048),  256, 0, stream>>>(pPART, b1, pD1);
  mlp_tail   <<<dim3(1000),  128, 0, stream>>>(pD1, pW2T, b2, pW3T, b3, Wout, bout, out);
}